// Round 3
// baseline (466.046 us; speedup 1.0000x reference)
//
#include <hip/hip_runtime.h>
#include <stdint.h>

#define E_DIM 512
#define NM 24
#define NC 48      // NM * 2 (re/im interleaved)
#define NCOL 96    // q(48) + k(48)
#define B_DIM 16
#define H_DIM 4096
#define NROWS (B_DIM * H_DIM)

// ---------- K1: build C[512][96], bias d[96], and M[48][512] in one launch ----------
__global__ __launch_bounds__(128)
void k_build(const float* __restrict__ Wq, const float* __restrict__ Wk,
             const float* __restrict__ bq, const float* __restrict__ bk,
             const int* __restrict__ idxq,
             float* __restrict__ C, float* __restrict__ dvec, float* __restrict__ M) {
  __shared__ float twc[E_DIM], tws[E_DIM];
  __shared__ int fj[NM];
  const int t = threadIdx.x;
  const int bid = blockIdx.x;
  if (bid >= E_DIM + 1) {
    // ---- M part: M[c][e] for gid in [0, 48*512) ----
    const int gid = (bid - (E_DIM + 1)) * 128 + t;
    const int c = gid >> 9;
    const int e = gid & (E_DIM - 1);
    const int j = c >> 1, p = c & 1;
    const int f = idxq[j];
    const float w = (f == 0 ? 1.0f : 2.0f) * (1.0f / (float)E_DIM);
    float s, cc;
    sincospif((float)((f * e) & (E_DIM - 1)) * (1.0f / 256.0f), &s, &cc);
    M[c * E_DIM + e] = p ? (-w * s) : (w * cc);
    return;
  }
  for (int i = t; i < E_DIM; i += 128) {
    float s, c;
    sincospif((float)i * (1.0f / 256.0f), &s, &c);   // angle = 2*pi*i/512
    twc[i] = c; tws[i] = s;
  }
  if (t < NM) fj[t] = idxq[t];
  __syncthreads();
  const int e = bid;                   // 0..511 = W column, 512 = bias row
  if (t >= NCOL) return;
  const int mat = t / NC;              // 0 = q, 1 = k
  const int c = t - mat * NC;
  const int j = c >> 1, p = c & 1;
  const int f = fj[j];
  float acc = 0.0f;
  if (e < E_DIM) {
    const float* __restrict__ W = mat ? Wk : Wq;
    for (int o = 0; o < E_DIM; ++o) {
      const float w = W[o * E_DIM + e];
      const int tt = (f * o) & (E_DIM - 1);
      acc = fmaf(w, p ? -tws[tt] : twc[tt], acc);
    }
    C[e * NCOL + t] = acc;
  } else {
    const float* __restrict__ bv = mat ? bk : bq;
    for (int o = 0; o < E_DIM; ++o) {
      const int tt = (f * o) & (E_DIM - 1);
      acc = fmaf(bv[o], p ? -tws[tt] : twc[tt], acc);
    }
    dvec[t] = acc;
  }
}

// ---------- K2: G[65536][96] = x @ C + d; also compact k-copy Gk[65536][48] ----------
// 512 threads, BM=256, 8x6 per-thread tile (acc=48). x-tile stored UNTRANSPOSED
// [row][32] packed so compute-phase x reads are 16-lane broadcasts (free banks).
#define GBM 256
#define GBK 32
__global__ __launch_bounds__(512)
void k_gemmG(const float* __restrict__ x, const float* __restrict__ C,
             const float* __restrict__ dvec, float* __restrict__ G,
             float* __restrict__ Gk) {
  __shared__ __align__(16) float xs[GBM * GBK];   // [row][k] packed, 32 KB
  __shared__ __align__(16) float cs[GBK * NCOL];  // [k][col] packed, 12 KB
  __shared__ float dsh[NCOL];
  const int t = threadIdx.x;
  const int ri = t >> 4;    // 0..31 -> rows ri*8 .. ri*8+7
  const int ci = t & 15;    // 0..15 -> cols ci*6 .. ci*6+5
  const int row0 = blockIdx.x * GBM;
  if (t < NCOL) dsh[t] = dvec[t];
  float acc[8][6];
#pragma unroll
  for (int a = 0; a < 8; ++a)
#pragma unroll
    for (int b = 0; b < 6; ++b) acc[a][b] = 0.0f;

  float4 xv[4], cv0, cv1;
  // prologue: stage k0 = 0 tile into registers
#pragma unroll
  for (int r = 0; r < 4; ++r) {
    const int idx = r * 512 + t;
    const int row = idx >> 3, kc = idx & 7;
    xv[r] = *(const float4*)&x[(size_t)(row0 + row) * E_DIM + kc * 4];
  }
  cv0 = *(const float4*)&C[t * 4];
  cv1 = make_float4(0.f, 0.f, 0.f, 0.f);
  if (t < 256) cv1 = *(const float4*)&C[(512 + t) * 4];

  for (int k0 = 0;; k0 += GBK) {
    __syncthreads();     // previous compute finished reading LDS
#pragma unroll
    for (int r = 0; r < 4; ++r) {
      const int idx = r * 512 + t;
      const int row = idx >> 3, kc = idx & 7;
      *(float4*)&xs[row * GBK + kc * 4] = xv[r];
    }
    *(float4*)&cs[t * 4] = cv0;
    if (t < 256) *(float4*)&cs[2048 + t * 4] = cv1;
    __syncthreads();
    const bool more = (k0 + GBK) < E_DIM;
    if (more) {
      const int kn = k0 + GBK;
#pragma unroll
      for (int r = 0; r < 4; ++r) {
        const int idx = r * 512 + t;
        const int row = idx >> 3, kc = idx & 7;
        xv[r] = *(const float4*)&x[(size_t)(row0 + row) * E_DIM + kn + kc * 4];
      }
      cv0 = *(const float4*)&C[kn * NCOL + t * 4];
      if (t < 256) cv1 = *(const float4*)&C[kn * NCOL + (512 + t) * 4];
    }
#pragma unroll 8
    for (int kk = 0; kk < GBK; ++kk) {
      float xr[8];
#pragma unroll
      for (int a = 0; a < 8; ++a) xr[a] = xs[(ri * 8 + a) * GBK + kk];
      const float2 c0 = *(const float2*)&cs[kk * NCOL + ci * 6 + 0];
      const float2 c1 = *(const float2*)&cs[kk * NCOL + ci * 6 + 2];
      const float2 c2 = *(const float2*)&cs[kk * NCOL + ci * 6 + 4];
      const float cc[6] = {c0.x, c0.y, c1.x, c1.y, c2.x, c2.y};
#pragma unroll
      for (int a = 0; a < 8; ++a)
#pragma unroll
        for (int b = 0; b < 6; ++b)
          acc[a][b] = fmaf(xr[a], cc[b], acc[a][b]);
    }
    if (!more) break;
  }
#pragma unroll
  for (int a = 0; a < 8; ++a) {
    const int row = row0 + ri * 8 + a;
    float v[6];
#pragma unroll
    for (int b = 0; b < 6; ++b) v[b] = acc[a][b] + dsh[ci * 6 + b];
#pragma unroll
    for (int b2 = 0; b2 < 3; ++b2) {
      float2 w2 = make_float2(v[b2 * 2], v[b2 * 2 + 1]);
      *(float2*)&G[(size_t)row * NCOL + ci * 6 + b2 * 2] = w2;
      if (ci >= 8)
        *(float2*)&Gk[(size_t)row * NC + (ci - 8) * 6 + b2 * 2] = w2;
    }
  }
}

// ---------- K3a: partial S over h-chunks: Sp[b][hc][24][24]{re,im} ----------
__global__ __launch_bounds__(576)
void k_spart(const float* __restrict__ G, float* __restrict__ Sp) {
  __shared__ __align__(16) float gs[128 * NCOL];    // 48 KB
  const int t = threadIdx.x;           // 0..575 = (x,y)
  const int xx = t / NM, yy = t - xx * NM;
  const int bc = blockIdx.x;           // b*32 + hc
  const int b = bc >> 5, hc = bc & 31;
  const int r0 = b * H_DIM + hc * 128;
  const float4* __restrict__ g4 = (const float4*)G;
#pragma unroll
  for (int r = 0; r < 6; ++r) {
    const int idx = t + r * 576;
    if (idx < 128 * NCOL / 4)
      ((float4*)gs)[idx] = g4[(size_t)r0 * (NCOL / 4) + idx];
  }
  __syncthreads();
  float sre = 0.0f, sim = 0.0f;
  for (int h = 0; h < 128; ++h) {
    const float2 q = *(const float2*)&gs[h * NCOL + 2 * xx];
    const float2 k = *(const float2*)&gs[h * NCOL + NC + 2 * yy];
    sre += q.x * k.x - q.y * k.y;      // complex product, no conjugation
    sim += q.x * k.y + q.y * k.x;
  }
  ((float2*)Sp)[bc * 576 + t] = make_float2(sre, sim);
}

// ---------- K3b: reduce chunks, |.|, row softmax -> att[b][24][24] ----------
__global__ __launch_bounds__(576)
void k_att(const float* __restrict__ Sp, float* __restrict__ att) {
  __shared__ float mag[576];
  __shared__ float ex[576];
  const int t = threadIdx.x;
  const int b = blockIdx.x;
  float sre = 0.0f, sim = 0.0f;
  const float2* in2 = (const float2*)Sp;
  for (int hc = 0; hc < 32; ++hc) {
    const float2 v = in2[(b * 32 + hc) * 576 + t];
    sre += v.x; sim += v.y;
  }
  mag[t] = sqrtf(sre * sre + sim * sim);
  __syncthreads();
  const int xx = t / NM;
  float m = -1e30f;
  for (int k = 0; k < NM; ++k) m = fmaxf(m, mag[xx * NM + k]);
  const float e = expf(mag[t] - m);
  ex[t] = e;
  __syncthreads();
  float s = 0.0f;
  for (int k = 0; k < NM; ++k) s += ex[xx * NM + k];
  att[b * 576 + t] = e / s;
}

// ---------- K4: fused Z + out: out[128 x 256 tile] = (att @ Gk_rows) @ M ----------
#define ZOB 128
#define ZON 256
__global__ __launch_bounds__(512)
void k_zout(const float* __restrict__ Gk, const float* __restrict__ M,
            const float* __restrict__ att, float* __restrict__ out) {
  __shared__ __align__(16) float ms[NC * ZON];      // 48 KB, [k][e] packed
  __shared__ __align__(16) float zs[NC][ZOB + 4];   // stride 132, 25.3 KB
  __shared__ float at[576];
  const int t = threadIdx.x;
  const int row0 = (blockIdx.x >> 1) * ZOB;
  const int e0 = (blockIdx.x & 1) * ZON;
  const int b = row0 >> 12;
  // issue M loads into regs (in flight across phase B)
  float4 mv[6];
#pragma unroll
  for (int r = 0; r < 6; ++r) {
    const int idx = r * 512 + t;          // f4 idx over [48][256]
    const int k = idx >> 6, ec = idx & 63;
    mv[r] = *(const float4*)&M[k * E_DIM + e0 + ec * 4];
  }
  at[t] = att[b * 576 + t];
  if (t < 64) at[512 + t] = att[b * 576 + 512 + t];
  __syncthreads();                        // at ready
#pragma unroll
  for (int r = 0; r < 6; ++r) {
    const int idx = r * 512 + t;
    *(float4*)&ms[idx * 4] = mv[r];
  }
  // ---- phase B: Z[row][48] = att-row-mix of Gk row (4 threads per row) ----
  const int zrow = t >> 2;                // 0..127
  const int xg = t & 3;                   // xx-group: xx = xg*6..xg*6+5
  float gk[NC];
  {
    const float4* gk4 = (const float4*)&Gk[(size_t)(row0 + zrow) * NC];
#pragma unroll
    for (int i = 0; i < 12; ++i) {
      const float4 v = gk4[i];
      gk[i * 4 + 0] = v.x; gk[i * 4 + 1] = v.y;
      gk[i * 4 + 2] = v.z; gk[i * 4 + 3] = v.w;
    }
  }
  float z[12];
#pragma unroll
  for (int j = 0; j < 6; ++j) {
    const int xx = xg * 6 + j;
    float zr = 0.0f, zi = 0.0f;
#pragma unroll
    for (int y = 0; y < NM; ++y) {
      const float a = at[xx * NM + y];
      zr = fmaf(a, gk[2 * y], zr);
      zi = fmaf(a, gk[2 * y + 1], zi);
    }
    z[2 * j] = zr; z[2 * j + 1] = zi;
  }
#pragma unroll
  for (int s = 0; s < 12; ++s) zs[xg * 12 + s][zrow] = z[s];
  __syncthreads();                        // zs + ms ready
  // ---- phase C: out tile = zs^T @ ms ----
  const int rr = t >> 4;                  // 0..31 -> rows rr*4..+3
  const int cg = t & 15;                  // cols cg*8..+7 and +128..
  float acc[4][16];
#pragma unroll
  for (int a = 0; a < 4; ++a)
#pragma unroll
    for (int c = 0; c < 16; ++c) acc[a][c] = 0.0f;
#pragma unroll 4
  for (int kk = 0; kk < NC; ++kk) {
    const float4 zv = *(const float4*)&zs[kk][rr * 4];
    const float4 m0 = *(const float4*)&ms[kk * ZON + cg * 8 + 0];
    const float4 m1 = *(const float4*)&ms[kk * ZON + cg * 8 + 4];
    const float4 m2 = *(const float4*)&ms[kk * ZON + cg * 8 + 128];
    const float4 m3 = *(const float4*)&ms[kk * ZON + cg * 8 + 132];
    const float zr[4] = {zv.x, zv.y, zv.z, zv.w};
    const float mr[16] = {m0.x, m0.y, m0.z, m0.w, m1.x, m1.y, m1.z, m1.w,
                          m2.x, m2.y, m2.z, m2.w, m3.x, m3.y, m3.z, m3.w};
#pragma unroll
    for (int a = 0; a < 4; ++a)
#pragma unroll
      for (int c = 0; c < 16; ++c)
        acc[a][c] = fmaf(zr[a], mr[c], acc[a][c]);
  }
#pragma unroll
  for (int a = 0; a < 4; ++a) {
    const int row = row0 + rr * 4 + a;
    float4 v0, v1, v2, v3;
    v0.x = acc[a][0];  v0.y = acc[a][1];  v0.z = acc[a][2];  v0.w = acc[a][3];
    v1.x = acc[a][4];  v1.y = acc[a][5];  v1.z = acc[a][6];  v1.w = acc[a][7];
    v2.x = acc[a][8];  v2.y = acc[a][9];  v2.z = acc[a][10]; v2.w = acc[a][11];
    v3.x = acc[a][12]; v3.y = acc[a][13]; v3.z = acc[a][14]; v3.w = acc[a][15];
    float* o = &out[(size_t)row * E_DIM + e0 + cg * 8];
    *(float4*)(o + 0)   = v0;
    *(float4*)(o + 4)   = v1;
    *(float4*)(o + 128) = v2;
    *(float4*)(o + 132) = v3;
  }
}

extern "C" void kernel_launch(void* const* d_in, const int* in_sizes, int n_in,
                              void* d_out, int out_size, void* d_ws, size_t ws_size,
                              hipStream_t stream) {
  const float* x  = (const float*)d_in[0];
  const float* Wq = (const float*)d_in[1];
  const float* bq = (const float*)d_in[2];
  const float* Wk = (const float*)d_in[3];
  const float* bk = (const float*)d_in[4];
  // d_in[5] (Wv), d_in[6] (bv): dead code in reference, never read
  const int* idxq = (const int*)d_in[7];
  float* out = (float*)d_out;
  float* ws = (float*)d_ws;

  // ws layout (floats): C 49152 | d 128 | M 24576 | att 9216 | Sp 589824 | Gk 3145728
  float* C   = ws;
  float* dv  = ws + 49152;
  float* M   = ws + 49280;
  float* att = ws + 73856;
  float* Sp  = ws + 83072;
  float* Gk  = ws + 672896;          // total ~14.6 MB of ws
  float* G   = out;                  // park G[65536][96] in d_out; dead before k_zout writes

  k_build<<<E_DIM + 1 + (NC * E_DIM) / 128, 128, 0, stream>>>(Wq, Wk, bq, bk, idxq, C, dv, M);
  k_gemmG<<<NROWS / GBM, 512, 0, stream>>>(x, C, dv, G, Gk);
  k_spart<<<B_DIM * 32, 576, 0, stream>>>(G, Sp);
  k_att<<<B_DIM, 576, 0, stream>>>(Sp, att);
  k_zout<<<(NROWS / ZOB) * (E_DIM / ZON), 512, 0, stream>>>(Gk, M, att, out);
}

// Round 5
// 405.063 us; speedup vs baseline: 1.1506x; 1.1506x over previous
//
#include <hip/hip_runtime.h>
#include <stdint.h>

#define E_DIM 512
#define NM 24
#define NC 48      // NM * 2 (re/im interleaved)
#define NCOL 96    // q(48) + k(48)
#define B_DIM 16
#define H_DIM 4096
#define NROWS (B_DIM * H_DIM)

typedef _Float16 half8 __attribute__((ext_vector_type(8)));
typedef float f32x4 __attribute__((ext_vector_type(4)));

// ---------- K1: build Ct hi/lo [96][512] f16, bias d[96], M[48][512] ----------
// Ct[c][e] = sum_o W[o][e] * {cos,-sin}(2*pi*f_j*o/512), split into f16 hi+lo.
__global__ __launch_bounds__(128)
void k_build(const float* __restrict__ Wq, const float* __restrict__ Wk,
             const float* __restrict__ bq, const float* __restrict__ bk,
             const int* __restrict__ idxq,
             _Float16* __restrict__ Cth, _Float16* __restrict__ Ctl,
             float* __restrict__ dvec, float* __restrict__ M) {
  __shared__ float twc[E_DIM], tws[E_DIM];
  __shared__ int fj[NM];
  const int t = threadIdx.x;
  const int bid = blockIdx.x;
  if (bid >= E_DIM + 1) {
    // ---- M part: M[c][e] for gid in [0, 48*512) ----
    const int gid = (bid - (E_DIM + 1)) * 128 + t;
    const int c = gid >> 9;
    const int e = gid & (E_DIM - 1);
    const int j = c >> 1, p = c & 1;
    const int f = idxq[j];
    const float w = (f == 0 ? 1.0f : 2.0f) * (1.0f / (float)E_DIM);
    float s, cc;
    sincospif((float)((f * e) & (E_DIM - 1)) * (1.0f / 256.0f), &s, &cc);
    M[c * E_DIM + e] = p ? (-w * s) : (w * cc);
    return;
  }
  for (int i = t; i < E_DIM; i += 128) {
    float s, c;
    sincospif((float)i * (1.0f / 256.0f), &s, &c);   // angle = 2*pi*i/512
    twc[i] = c; tws[i] = s;
  }
  if (t < NM) fj[t] = idxq[t];
  __syncthreads();
  const int e = bid;                   // 0..511 = W column, 512 = bias row
  if (t >= NCOL) return;
  const int mat = t / NC;              // 0 = q, 1 = k
  const int c = t - mat * NC;
  const int j = c >> 1, p = c & 1;
  const int f = fj[j];
  float acc = 0.0f;
  if (e < E_DIM) {
    const float* __restrict__ W = mat ? Wk : Wq;
    for (int o = 0; o < E_DIM; ++o) {
      const float w = W[o * E_DIM + e];
      const int tt = (f * o) & (E_DIM - 1);
      acc = fmaf(w, p ? -tws[tt] : twc[tt], acc);
    }
    const _Float16 hi = (_Float16)acc;
    Cth[t * E_DIM + e] = hi;
    Ctl[t * E_DIM + e] = (_Float16)(acc - (float)hi);
  } else {
    const float* __restrict__ bv = mat ? bk : bq;
    for (int o = 0; o < E_DIM; ++o) {
      const int tt = (f * o) & (E_DIM - 1);
      acc = fmaf(bv[o], p ? -tws[tt] : twc[tt], acc);
    }
    dvec[t] = acc;
  }
}

// ---------- K2: G[65536][96] = x @ C + d via split-f16 MFMA ----------
// D[m=c][n=row]; A = Ct (f16 hi/lo from L2), B = x frags direct from global.
// Wave: 64 rows x 96 cols, acc 6x4 tiles. No LDS, no barriers.
__global__ __launch_bounds__(256)
void k_gemmG(const float* __restrict__ x, const _Float16* __restrict__ Cth,
             const _Float16* __restrict__ Ctl, const float* __restrict__ dvec,
             float* __restrict__ G, float* __restrict__ Gk) {
  const int t = threadIdx.x;
  const int lane = t & 63;
  const int wv = t >> 6;               // 0..3
  const int rb = blockIdx.x * 256 + wv * 64;
  const int lm = lane & 15;            // A: c-within-tile / B,D: row-within-tile
  const int lk = lane >> 4;            // k-group (and D: c-reg group)
  f32x4 acc[6][4];
#pragma unroll
  for (int mt = 0; mt < 6; ++mt)
#pragma unroll
    for (int nt = 0; nt < 4; ++nt) acc[mt][nt] = (f32x4){0.f, 0.f, 0.f, 0.f};

  for (int k0 = 0; k0 < E_DIM; k0 += 32) {
    half8 xh[4], xl[4];
#pragma unroll
    for (int nt = 0; nt < 4; ++nt) {
      const float* __restrict__ xp =
          &x[(size_t)(rb + nt * 16 + lm) * E_DIM + k0 + lk * 8];
      const float4 v0 = *(const float4*)xp;
      const float4 v1 = *(const float4*)(xp + 4);
      const float vv[8] = {v0.x, v0.y, v0.z, v0.w, v1.x, v1.y, v1.z, v1.w};
#pragma unroll
      for (int i = 0; i < 8; ++i) {
        const _Float16 h = (_Float16)vv[i];
        xh[nt][i] = h;
        xl[nt][i] = (_Float16)(vv[i] - (float)h);
      }
    }
#pragma unroll
    for (int mt = 0; mt < 6; ++mt) {
      const int arow = mt * 16 + lm;
      const half8 Ah = *(const half8*)&Cth[arow * E_DIM + k0 + lk * 8];
      const half8 Al = *(const half8*)&Ctl[arow * E_DIM + k0 + lk * 8];
#pragma unroll
      for (int nt = 0; nt < 4; ++nt) {
        acc[mt][nt] = __builtin_amdgcn_mfma_f32_16x16x32_f16(Ah, xh[nt], acc[mt][nt], 0, 0, 0);
        acc[mt][nt] = __builtin_amdgcn_mfma_f32_16x16x32_f16(Al, xh[nt], acc[mt][nt], 0, 0, 0);
        acc[mt][nt] = __builtin_amdgcn_mfma_f32_16x16x32_f16(Ah, xl[nt], acc[mt][nt], 0, 0, 0);
      }
    }
  }
  // epilogue: D[m = lk*4+reg][n = lm] -> c = mt*16+lk*4+reg, r = rb+nt*16+lm
#pragma unroll
  for (int mt = 0; mt < 6; ++mt) {
    const int c0 = mt * 16 + lk * 4;
    const float4 bias = *(const float4*)&dvec[c0];
#pragma unroll
    for (int nt = 0; nt < 4; ++nt) {
      const int r = rb + nt * 16 + lm;
      float4 st;
      st.x = acc[mt][nt][0] + bias.x;
      st.y = acc[mt][nt][1] + bias.y;
      st.z = acc[mt][nt][2] + bias.z;
      st.w = acc[mt][nt][3] + bias.w;
      *(float4*)&G[(size_t)r * NCOL + c0] = st;
      if (mt >= 3)
        *(float4*)&Gk[(size_t)r * NC + (c0 - NC)] = st;
    }
  }
}

// ---------- K3a: partial S over h-chunks: Sp[b][hc][24][24]{re,im} ----------
__global__ __launch_bounds__(576)
void k_spart(const float* __restrict__ G, float* __restrict__ Sp) {
  __shared__ __align__(16) float gs[128 * NCOL];    // 48 KB
  const int t = threadIdx.x;           // 0..575 = (x,y)
  const int xx = t / NM, yy = t - xx * NM;
  const int bc = blockIdx.x;           // b*32 + hc
  const int b = bc >> 5, hc = bc & 31;
  const int r0 = b * H_DIM + hc * 128;
  const float4* __restrict__ g4 = (const float4*)G;
#pragma unroll
  for (int r = 0; r < 6; ++r) {
    const int idx = t + r * 576;
    if (idx < 128 * NCOL / 4)
      ((float4*)gs)[idx] = g4[(size_t)r0 * (NCOL / 4) + idx];
  }
  __syncthreads();
  float sre = 0.0f, sim = 0.0f;
  for (int h = 0; h < 128; ++h) {
    const float2 q = *(const float2*)&gs[h * NCOL + 2 * xx];
    const float2 k = *(const float2*)&gs[h * NCOL + NC + 2 * yy];
    sre += q.x * k.x - q.y * k.y;      // complex product, no conjugation
    sim += q.x * k.y + q.y * k.x;
  }
  ((float2*)Sp)[bc * 576 + t] = make_float2(sre, sim);
}

// ---------- K3b: reduce chunks, |.|, row softmax -> att[b][24][24] ----------
__global__ __launch_bounds__(576)
void k_att(const float* __restrict__ Sp, float* __restrict__ att) {
  __shared__ float mag[576];
  __shared__ float ex[576];
  const int t = threadIdx.x;
  const int b = blockIdx.x;
  float sre = 0.0f, sim = 0.0f;
  const float2* in2 = (const float2*)Sp;
  for (int hc = 0; hc < 32; ++hc) {
    const float2 v = in2[(b * 32 + hc) * 576 + t];
    sre += v.x; sim += v.y;
  }
  mag[t] = sqrtf(sre * sre + sim * sim);
  __syncthreads();
  const int xx = t / NM;
  float m = -1e30f;
  for (int k = 0; k < NM; ++k) m = fmaxf(m, mag[xx * NM + k]);
  const float e = expf(mag[t] - m);
  ex[t] = e;
  __syncthreads();
  float s = 0.0f;
  for (int k = 0; k < NM; ++k) s += ex[xx * NM + k];
  att[b * 576 + t] = e / s;
}

// ---------- K4: fused Z + out: out[128 x 256 tile] = (att @ Gk_rows) @ M ----------
#define ZOB 128
#define ZON 256
__global__ __launch_bounds__(512)
void k_zout(const float* __restrict__ Gk, const float* __restrict__ M,
            const float* __restrict__ att, float* __restrict__ out) {
  __shared__ __align__(16) float ms[NC * ZON];      // 48 KB, [k][e] packed
  __shared__ __align__(16) float zs[NC][ZOB + 4];   // stride 132, 25.3 KB
  __shared__ float at[576];
  const int t = threadIdx.x;
  const int row0 = (blockIdx.x >> 1) * ZOB;
  const int e0 = (blockIdx.x & 1) * ZON;
  const int b = row0 >> 12;
  // issue M loads into regs (in flight across phase B)
  float4 mv[6];
#pragma unroll
  for (int r = 0; r < 6; ++r) {
    const int idx = r * 512 + t;          // f4 idx over [48][256]
    const int k = idx >> 6, ec = idx & 63;
    mv[r] = *(const float4*)&M[k * E_DIM + e0 + ec * 4];
  }
  at[t] = att[b * 576 + t];
  if (t < 64) at[512 + t] = att[b * 576 + 512 + t];
  __syncthreads();                        // at ready
#pragma unroll
  for (int r = 0; r < 6; ++r) {
    const int idx = r * 512 + t;
    *(float4*)&ms[idx * 4] = mv[r];
  }
  // ---- phase B: Z[row][48] = att-row-mix of Gk row (4 threads per row) ----
  const int zrow = t >> 2;                // 0..127
  const int xg = t & 3;                   // xx-group: xx = xg*6..xg*6+5
  float gk[NC];
  {
    const float4* gk4 = (const float4*)&Gk[(size_t)(row0 + zrow) * NC];
#pragma unroll
    for (int i = 0; i < 12; ++i) {
      const float4 v = gk4[i];
      gk[i * 4 + 0] = v.x; gk[i * 4 + 1] = v.y;
      gk[i * 4 + 2] = v.z; gk[i * 4 + 3] = v.w;
    }
  }
  float z[12];
#pragma unroll
  for (int j = 0; j < 6; ++j) {
    const int xx = xg * 6 + j;
    float zr = 0.0f, zi = 0.0f;
#pragma unroll
    for (int y = 0; y < NM; ++y) {
      const float a = at[xx * NM + y];
      zr = fmaf(a, gk[2 * y], zr);
      zi = fmaf(a, gk[2 * y + 1], zi);
    }
    z[2 * j] = zr; z[2 * j + 1] = zi;
  }
#pragma unroll
  for (int s = 0; s < 12; ++s) zs[xg * 12 + s][zrow] = z[s];
  __syncthreads();                        // zs + ms ready
  // ---- phase C: out tile = zs^T @ ms ----
  const int rr = t >> 4;                  // 0..31 -> rows rr*4..+3
  const int cg = t & 15;                  // cols cg*8..+7 and +128..
  float acc[4][16];
#pragma unroll
  for (int a = 0; a < 4; ++a)
#pragma unroll
    for (int c = 0; c < 16; ++c) acc[a][c] = 0.0f;
#pragma unroll 4
  for (int kk = 0; kk < NC; ++kk) {
    const float4 zv = *(const float4*)&zs[kk][rr * 4];
    const float4 m0 = *(const float4*)&ms[kk * ZON + cg * 8 + 0];
    const float4 m1 = *(const float4*)&ms[kk * ZON + cg * 8 + 4];
    const float4 m2 = *(const float4*)&ms[kk * ZON + cg * 8 + 128];
    const float4 m3 = *(const float4*)&ms[kk * ZON + cg * 8 + 132];
    const float zr[4] = {zv.x, zv.y, zv.z, zv.w};
    const float mr[16] = {m0.x, m0.y, m0.z, m0.w, m1.x, m1.y, m1.z, m1.w,
                          m2.x, m2.y, m2.z, m2.w, m3.x, m3.y, m3.z, m3.w};
#pragma unroll
    for (int a = 0; a < 4; ++a)
#pragma unroll
      for (int c = 0; c < 16; ++c)
        acc[a][c] = fmaf(zr[a], mr[c], acc[a][c]);
  }
#pragma unroll
  for (int a = 0; a < 4; ++a) {
    const int row = row0 + rr * 4 + a;
    float4 v0, v1, v2, v3;
    v0.x = acc[a][0];  v0.y = acc[a][1];  v0.z = acc[a][2];  v0.w = acc[a][3];
    v1.x = acc[a][4];  v1.y = acc[a][5];  v1.z = acc[a][6];  v1.w = acc[a][7];
    v2.x = acc[a][8];  v2.y = acc[a][9];  v2.z = acc[a][10]; v2.w = acc[a][11];
    v3.x = acc[a][12]; v3.y = acc[a][13]; v3.z = acc[a][14]; v3.w = acc[a][15];
    float* o = &out[(size_t)row * E_DIM + e0 + cg * 8];
    *(float4*)(o + 0)   = v0;
    *(float4*)(o + 4)   = v1;
    *(float4*)(o + 128) = v2;
    *(float4*)(o + 132) = v3;
  }
}

extern "C" void kernel_launch(void* const* d_in, const int* in_sizes, int n_in,
                              void* d_out, int out_size, void* d_ws, size_t ws_size,
                              hipStream_t stream) {
  const float* x  = (const float*)d_in[0];
  const float* Wq = (const float*)d_in[1];
  const float* bq = (const float*)d_in[2];
  const float* Wk = (const float*)d_in[3];
  const float* bk = (const float*)d_in[4];
  // d_in[5] (Wv), d_in[6] (bv): dead code in reference, never read
  const int* idxq = (const int*)d_in[7];
  float* out = (float*)d_out;
  float* ws = (float*)d_ws;

  // ws layout (floats): Cth 24576 | Ctl 24576 | d 128 | M 24576 | att 9216 | Sp 589824 | Gk 3145728
  _Float16* Cth = (_Float16*)ws;
  _Float16* Ctl = (_Float16*)(ws + 24576);
  float* dv  = ws + 49152;
  float* M   = ws + 49280;
  float* att = ws + 73856;
  float* Sp  = ws + 83072;
  float* Gk  = ws + 672896;          // total ~14.6 MB of ws
  float* G   = out;                  // park G[65536][96] in d_out; dead before k_zout writes

  k_build<<<E_DIM + 1 + (NC * E_DIM) / 128, 128, 0, stream>>>(Wq, Wk, bq, bk, idxq, Cth, Ctl, dv, M);
  k_gemmG<<<NROWS / 256, 256, 0, stream>>>(x, Cth, Ctl, dv, G, Gk);
  k_spart<<<B_DIM * 32, 576, 0, stream>>>(G, Sp);
  k_att<<<B_DIM, 576, 0, stream>>>(Sp, att);
  k_zout<<<(NROWS / ZOB) * (E_DIM / ZON), 512, 0, stream>>>(Gk, M, att, out);
}

// Round 6
// 357.915 us; speedup vs baseline: 1.3021x; 1.1317x over previous
//
#include <hip/hip_runtime.h>
#include <stdint.h>

#define E_DIM 512
#define NM 24
#define NC 48      // NM * 2 (re/im interleaved)
#define NCOL 96    // q(48) + k(48)
#define B_DIM 16
#define H_DIM 4096
#define NROWS (B_DIM * H_DIM)
#define NPAIR 576  // 24 x 24

typedef _Float16 half8 __attribute__((ext_vector_type(8)));
typedef float f32x4 __attribute__((ext_vector_type(4)));

// ---------- K1: build Ct hi/lo [96][512] f16 + bias d[96] + M[48][512] ----------
// blocks 0..95: C row c (coalesced W reads) + bias via wave-reduce.
// blocks 96..143: M row c-96.
__global__ __launch_bounds__(512)
void k_build(const float* __restrict__ Wq, const float* __restrict__ Wk,
             const float* __restrict__ bq, const float* __restrict__ bk,
             const int* __restrict__ idxq,
             _Float16* __restrict__ Cth, _Float16* __restrict__ Ctl,
             float* __restrict__ dvec, float* __restrict__ M) {
  const int t = threadIdx.x;
  const int bid = blockIdx.x;
  if (bid >= NCOL) {
    // ---- M rows ----
    const int c = bid - NCOL;
    const int j = c >> 1, p = c & 1;
    const int f = idxq[j];
    const float w = (f == 0 ? 1.0f : 2.0f) * (1.0f / (float)E_DIM);
    float s, cc;
    sincospif((float)((f * t) & (E_DIM - 1)) * (1.0f / 256.0f), &s, &cc);
    M[c * E_DIM + t] = p ? (-w * s) : (w * cc);
    return;
  }
  // ---- C row c = bid ----
  __shared__ float tw[E_DIM];
  const int mat = bid / NC;            // 0 = q, 1 = k
  const int c = bid - mat * NC;
  const int j = c >> 1, p = c & 1;
  const int f = idxq[j];
  {
    float s, cc;
    sincospif((float)((f * t) & (E_DIM - 1)) * (1.0f / 256.0f), &s, &cc);
    tw[t] = p ? -s : cc;
  }
  __syncthreads();
  const float* __restrict__ W = mat ? Wk : Wq;
  float acc = 0.0f;
#pragma unroll 8
  for (int o = 0; o < E_DIM; ++o)
    acc = fmaf(W[o * E_DIM + t], tw[o], acc);
  const _Float16 hi = (_Float16)acc;
  Cth[bid * E_DIM + t] = hi;
  Ctl[bid * E_DIM + t] = (_Float16)(acc - (float)hi);
  // bias: wave 0 reduces b . tw
  if (t < 64) {
    const float* __restrict__ bv = mat ? bk : bq;
    float ba = 0.0f;
#pragma unroll
    for (int r = 0; r < 8; ++r) {
      const int o = r * 64 + t;
      ba = fmaf(bv[o], tw[o], ba);
    }
#pragma unroll
    for (int off = 32; off > 0; off >>= 1)
      ba += __shfl_down(ba, off, 64);
    if (t == 0) dvec[bid] = ba;
  }
}

// ---------- K2: fused G-gemm + partial-S ----------
// MFMA: D[m=c][n=row], A = Ct f16 hi/lo (L2), B = x frags direct from global.
// Wave: 64 rows x 96 cols. Then per 128-row half: stage G in LDS, accumulate
// complex S partials for all 576 (x,y) pairs. Emit Gk (k-part, for zout) and
// Sp[block][576]{re,im}. Never materializes G in HBM.
#define GSTR 100   // LDS row stride (floats): 100%32=4 -> writes ~2-way (free)
__global__ __launch_bounds__(256)
void k_gemmG(const float* __restrict__ x, const _Float16* __restrict__ Cth,
             const _Float16* __restrict__ Ctl, const float* __restrict__ dvec,
             float* __restrict__ Gk, float* __restrict__ Sp) {
  __shared__ __align__(16) float gs[128 * GSTR];   // 51.2 KB
  const int t = threadIdx.x;
  const int lane = t & 63;
  const int wv = t >> 6;               // 0..3
  const int rb = blockIdx.x * 256 + wv * 64;
  const int lm = lane & 15;            // A: c-within-tile / B,D: row-within-tile
  const int lk = lane >> 4;            // k-group (and D: c-reg group)
  f32x4 acc[6][4];
#pragma unroll
  for (int mt = 0; mt < 6; ++mt)
#pragma unroll
    for (int nt = 0; nt < 4; ++nt) acc[mt][nt] = (f32x4){0.f, 0.f, 0.f, 0.f};

  for (int k0 = 0; k0 < E_DIM; k0 += 32) {
    half8 xh[4], xl[4];
#pragma unroll
    for (int nt = 0; nt < 4; ++nt) {
      const float* __restrict__ xp =
          &x[(size_t)(rb + nt * 16 + lm) * E_DIM + k0 + lk * 8];
      const float4 v0 = *(const float4*)xp;
      const float4 v1 = *(const float4*)(xp + 4);
      const float vv[8] = {v0.x, v0.y, v0.z, v0.w, v1.x, v1.y, v1.z, v1.w};
#pragma unroll
      for (int i = 0; i < 8; ++i) {
        const _Float16 h = (_Float16)vv[i];
        xh[nt][i] = h;
        xl[nt][i] = (_Float16)(vv[i] - (float)h);
      }
    }
#pragma unroll
    for (int mt = 0; mt < 6; ++mt) {
      const int arow = mt * 16 + lm;
      const half8 Ah = *(const half8*)&Cth[arow * E_DIM + k0 + lk * 8];
      const half8 Al = *(const half8*)&Ctl[arow * E_DIM + k0 + lk * 8];
#pragma unroll
      for (int nt = 0; nt < 4; ++nt) {
        acc[mt][nt] = __builtin_amdgcn_mfma_f32_16x16x32_f16(Ah, xh[nt], acc[mt][nt], 0, 0, 0);
        acc[mt][nt] = __builtin_amdgcn_mfma_f32_16x16x32_f16(Al, xh[nt], acc[mt][nt], 0, 0, 0);
        acc[mt][nt] = __builtin_amdgcn_mfma_f32_16x16x32_f16(Ah, xl[nt], acc[mt][nt], 0, 0, 0);
      }
    }
  }
  // bias add in-place; write Gk (k-part) to global
#pragma unroll
  for (int mt = 0; mt < 6; ++mt) {
    const int c0 = mt * 16 + lk * 4;
    const float4 bias = *(const float4*)&dvec[c0];
#pragma unroll
    for (int nt = 0; nt < 4; ++nt) {
      acc[mt][nt][0] += bias.x;
      acc[mt][nt][1] += bias.y;
      acc[mt][nt][2] += bias.z;
      acc[mt][nt][3] += bias.w;
      if (mt >= 3) {
        const int r = rb + nt * 16 + lm;
        float4 st;
        st.x = acc[mt][nt][0]; st.y = acc[mt][nt][1];
        st.z = acc[mt][nt][2]; st.w = acc[mt][nt][3];
        *(float4*)&Gk[(size_t)r * NC + (c0 - NC)] = st;
      }
    }
  }
  // ---- partial S over this block's 256 rows, in 2 half-blocks of 128 ----
  float sre[3] = {0.f, 0.f, 0.f}, sim[3] = {0.f, 0.f, 0.f};
#pragma unroll
  for (int half = 0; half < 2; ++half) {
    __syncthreads();                   // prev half's reads done
    if ((wv >> 1) == half) {
#pragma unroll
      for (int mt = 0; mt < 6; ++mt) {
        const int c0 = mt * 16 + lk * 4;
#pragma unroll
        for (int nt = 0; nt < 4; ++nt) {
          const int lrow = (wv & 1) * 64 + nt * 16 + lm;
          float4 st;
          st.x = acc[mt][nt][0]; st.y = acc[mt][nt][1];
          st.z = acc[mt][nt][2]; st.w = acc[mt][nt][3];
          *(float4*)&gs[lrow * GSTR + c0] = st;
        }
      }
    }
    __syncthreads();                   // gs ready
#pragma unroll
    for (int r = 0; r < 3; ++r) {
      const int i = t + r * 256;
      if (i < NPAIR) {
        const int xx = i / NM, yy = i - xx * NM;
        float ar = 0.f, ai = 0.f;
        for (int h = 0; h < 128; ++h) {
          const float2 q = *(const float2*)&gs[h * GSTR + 2 * xx];
          const float2 k = *(const float2*)&gs[h * GSTR + NC + 2 * yy];
          ar += q.x * k.x - q.y * k.y;   // complex product, no conjugation
          ai += q.x * k.y + q.y * k.x;
        }
        sre[r] += ar; sim[r] += ai;
      }
    }
  }
#pragma unroll
  for (int r = 0; r < 3; ++r) {
    const int i = t + r * 256;
    if (i < NPAIR)
      ((float2*)Sp)[(size_t)blockIdx.x * NPAIR + i] = make_float2(sre[r], sim[r]);
  }
}

// ---------- K3: reduce 16 chunks/batch, |.|, row softmax -> att[b][24][24] ----------
__global__ __launch_bounds__(576)
void k_att(const float* __restrict__ Sp, float* __restrict__ att) {
  __shared__ float mag[NPAIR];
  __shared__ float ex[NPAIR];
  const int t = threadIdx.x;
  const int b = blockIdx.x;
  float sre = 0.0f, sim = 0.0f;
  const float2* in2 = (const float2*)Sp;
  for (int hc = 0; hc < 16; ++hc) {
    const float2 v = in2[(size_t)(b * 16 + hc) * NPAIR + t];
    sre += v.x; sim += v.y;
  }
  mag[t] = sqrtf(sre * sre + sim * sim);
  __syncthreads();
  const int xx = t / NM;
  float m = -1e30f;
  for (int k = 0; k < NM; ++k) m = fmaxf(m, mag[xx * NM + k]);
  const float e = expf(mag[t] - m);
  ex[t] = e;
  __syncthreads();
  float s = 0.0f;
  for (int k = 0; k < NM; ++k) s += ex[xx * NM + k];
  att[b * NPAIR + t] = e / s;
}

// ---------- K4: fused Z + out: out[128 x 256 tile] = (att @ Gk_rows) @ M ----------
#define ZOB 128
#define ZON 256
__global__ __launch_bounds__(512)
void k_zout(const float* __restrict__ Gk, const float* __restrict__ M,
            const float* __restrict__ att, float* __restrict__ out) {
  __shared__ __align__(16) float ms[NC * ZON];      // 48 KB, [k][e] packed
  __shared__ __align__(16) float zs[NC][ZOB + 4];   // stride 132, 25.3 KB
  __shared__ float at[NPAIR];
  const int t = threadIdx.x;
  const int row0 = (blockIdx.x >> 1) * ZOB;
  const int e0 = (blockIdx.x & 1) * ZON;
  const int b = row0 >> 12;
  // issue M loads into regs (in flight across phase B)
  float4 mv[6];
#pragma unroll
  for (int r = 0; r < 6; ++r) {
    const int idx = r * 512 + t;          // f4 idx over [48][256]
    const int k = idx >> 6, ec = idx & 63;
    mv[r] = *(const float4*)&M[k * E_DIM + e0 + ec * 4];
  }
  at[t] = att[b * NPAIR + t];
  if (t < 64) at[512 + t] = att[b * NPAIR + 512 + t];
  __syncthreads();                        // at ready
#pragma unroll
  for (int r = 0; r < 6; ++r) {
    const int idx = r * 512 + t;
    *(float4*)&ms[idx * 4] = mv[r];
  }
  // ---- phase B: Z[row][48] = att-row-mix of Gk row (4 threads per row) ----
  const int zrow = t >> 2;                // 0..127
  const int xg = t & 3;                   // xx-group: xx = xg*6..xg*6+5
  float gk[NC];
  {
    const float4* gk4 = (const float4*)&Gk[(size_t)(row0 + zrow) * NC];
#pragma unroll
    for (int i = 0; i < 12; ++i) {
      const float4 v = gk4[i];
      gk[i * 4 + 0] = v.x; gk[i * 4 + 1] = v.y;
      gk[i * 4 + 2] = v.z; gk[i * 4 + 3] = v.w;
    }
  }
  float z[12];
#pragma unroll
  for (int j = 0; j < 6; ++j) {
    const int xx = xg * 6 + j;
    float zr = 0.0f, zi = 0.0f;
#pragma unroll
    for (int y = 0; y < NM; ++y) {
      const float a = at[xx * NM + y];
      zr = fmaf(a, gk[2 * y], zr);
      zi = fmaf(a, gk[2 * y + 1], zi);
    }
    z[2 * j] = zr; z[2 * j + 1] = zi;
  }
#pragma unroll
  for (int s = 0; s < 12; ++s) zs[xg * 12 + s][zrow] = z[s];
  __syncthreads();                        // zs + ms ready
  // ---- phase C: out tile = zs^T @ ms ----
  const int rr = t >> 4;                  // 0..31 -> rows rr*4..+3
  const int cg = t & 15;                  // cols cg*8..+7 and +128..
  float acc[4][16];
#pragma unroll
  for (int a = 0; a < 4; ++a)
#pragma unroll
    for (int c = 0; c < 16; ++c) acc[a][c] = 0.0f;
#pragma unroll 4
  for (int kk = 0; kk < NC; ++kk) {
    const float4 zv = *(const float4*)&zs[kk][rr * 4];
    const float4 m0 = *(const float4*)&ms[kk * ZON + cg * 8 + 0];
    const float4 m1 = *(const float4*)&ms[kk * ZON + cg * 8 + 4];
    const float4 m2 = *(const float4*)&ms[kk * ZON + cg * 8 + 128];
    const float4 m3 = *(const float4*)&ms[kk * ZON + cg * 8 + 132];
    const float zr[4] = {zv.x, zv.y, zv.z, zv.w};
    const float mr[16] = {m0.x, m0.y, m0.z, m0.w, m1.x, m1.y, m1.z, m1.w,
                          m2.x, m2.y, m2.z, m2.w, m3.x, m3.y, m3.z, m3.w};
#pragma unroll
    for (int a = 0; a < 4; ++a)
#pragma unroll
      for (int c = 0; c < 16; ++c)
        acc[a][c] = fmaf(zr[a], mr[c], acc[a][c]);
  }
#pragma unroll
  for (int a = 0; a < 4; ++a) {
    const int row = row0 + rr * 4 + a;
    float4 v0, v1, v2, v3;
    v0.x = acc[a][0];  v0.y = acc[a][1];  v0.z = acc[a][2];  v0.w = acc[a][3];
    v1.x = acc[a][4];  v1.y = acc[a][5];  v1.z = acc[a][6];  v1.w = acc[a][7];
    v2.x = acc[a][8];  v2.y = acc[a][9];  v2.z = acc[a][10]; v2.w = acc[a][11];
    v3.x = acc[a][12]; v3.y = acc[a][13]; v3.z = acc[a][14]; v3.w = acc[a][15];
    float* o = &out[(size_t)row * E_DIM + e0 + cg * 8];
    *(float4*)(o + 0)   = v0;
    *(float4*)(o + 4)   = v1;
    *(float4*)(o + 128) = v2;
    *(float4*)(o + 132) = v3;
  }
}

extern "C" void kernel_launch(void* const* d_in, const int* in_sizes, int n_in,
                              void* d_out, int out_size, void* d_ws, size_t ws_size,
                              hipStream_t stream) {
  const float* x  = (const float*)d_in[0];
  const float* Wq = (const float*)d_in[1];
  const float* bq = (const float*)d_in[2];
  const float* Wk = (const float*)d_in[3];
  const float* bk = (const float*)d_in[4];
  // d_in[5] (Wv), d_in[6] (bv): dead code in reference, never read
  const int* idxq = (const int*)d_in[7];
  float* out = (float*)d_out;
  float* ws = (float*)d_ws;

  // ws layout (floats): Cth 24576 | Ctl 24576 | d 128 | M 24576 | att 9216 | Sp 294912 | Gk 3145728
  _Float16* Cth = (_Float16*)ws;
  _Float16* Ctl = (_Float16*)(ws + 24576);
  float* dv  = ws + 49152;
  float* M   = ws + 49280;
  float* att = ws + 73856;
  float* Sp  = ws + 83072;
  float* Gk  = ws + 377984;          // total ~14.1 MB of ws

  k_build<<<NCOL + NC, 512, 0, stream>>>(Wq, Wk, bq, bk, idxq, Cth, Ctl, dv, M);
  k_gemmG<<<NROWS / 256, 256, 0, stream>>>(x, Cth, Ctl, dv, Gk, Sp);
  k_att<<<B_DIM, 576, 0, stream>>>(Sp, att);
  k_zout<<<(NROWS / ZOB) * (E_DIM / ZON), 512, 0, stream>>>(Gk, M, att, out);
}